// Round 6
// baseline (235.407 us; speedup 1.0000x reference)
//
#include <hip/hip_runtime.h>
#include <math.h>

constexpr int D = 128;

typedef __attribute__((ext_vector_type(8))) short short8;
typedef __attribute__((ext_vector_type(4))) float f32x4;
typedef unsigned short ushort_t;
typedef unsigned int uint_t;

__device__ inline ushort_t f2b(float x) {          // fp32 -> bf16 RNE
    uint_t u = __float_as_uint(x);
    uint_t r = u + 0x7fffu + ((u >> 16) & 1u);
    return (ushort_t)(r >> 16);
}
__device__ inline float b2f(ushort_t b) { return __uint_as_float(((uint_t)b) << 16); }

__device__ inline float sigm(float x) { return 1.f / (1.f + __expf(-x)); }
__device__ inline float tanh_(float x) {
    float t = __expf(-2.f * fabsf(x));
    float y = (1.f - t) / (1.f + t);
    return x >= 0.f ? y : -y;
}

// ---- convert weights to bf16 ---------------------------------------------
__global__ __launch_bounds__(256) void k_prep_w(
    const float* __restrict__ W_ih, const float* __restrict__ W_hh,
    const float* __restrict__ W_proj,
    ushort_t* __restrict__ Wih16, ushort_t* __restrict__ Whh16,
    ushort_t* __restrict__ WpT16)
{
    int idx = blockIdx.x * 256 + threadIdx.x;
    if (idx < 49152) {
        Wih16[idx] = f2b(W_ih[idx]);
    } else if (idx < 98304) {
        int i = idx - 49152;
        Whh16[i] = f2b(W_hh[i]);
    } else if (idx < 114688) {
        int t = idx - 98304;           // WpT[j][k] = W_proj[k][j]
        int j = t >> 7, k = t & 127;
        WpT16[t] = f2b(W_proj[k * 128 + j]);
    }
}

// ---- fused: nf->bf16, edge scores, hv = nf@WpT+b (MFMA, W in LDS) --------
__global__ __launch_bounds__(256, 2) void k_hv_fused(
    const float* __restrict__ nf, const ushort_t* __restrict__ WpT16,
    const float* __restrict__ b_proj, const float* __restrict__ W_edge,
    ushort_t* __restrict__ nf16, ushort_t* __restrict__ hv16,
    float* __restrict__ s_d, float* __restrict__ s_s, int N)
{
    __shared__ ushort_t plds[16384];           // 128 x 128 bf16 = 32 KB
    int w = threadIdx.x >> 6, lane = threadIdx.x & 63;
    int am = lane & 15, hi = lane >> 4, ak = hi * 8;

    // stage WpT into LDS once (swizzled: slot ^= row&15)
#pragma unroll
    for (int i = 0; i < 8; ++i) {
        int dl = (w * 8 + i) * 4 + hi;         // 0..127
        short8 v = *(const short8*)(WpT16 + (size_t)dl * 128 + am * 8);
        *(short8*)(plds + dl * 128 + ((am ^ (dl & 15)) * 8)) = v;
    }

    int r0 = blockIdx.x * 64 + w * 16;
    int arow = r0 + am;
    bool aok = arow < N;
    short8 A[4];
    float pd = 0.f, ps = 0.f;
#pragma unroll
    for (int kf = 0; kf < 4; ++kf) {
        int ko = kf * 32 + ak;
        float4 f0 = {0,0,0,0}, f1 = {0,0,0,0};
        if (aok) {
            f0 = *(const float4*)(nf + (size_t)arow * 128 + ko);
            f1 = *(const float4*)(nf + (size_t)arow * 128 + ko + 4);
        }
        pd += f0.x * W_edge[ko]     + f0.y * W_edge[ko + 1]
            + f0.z * W_edge[ko + 2] + f0.w * W_edge[ko + 3]
            + f1.x * W_edge[ko + 4] + f1.y * W_edge[ko + 5]
            + f1.z * W_edge[ko + 6] + f1.w * W_edge[ko + 7];
        ps += f0.x * W_edge[128+ko]     + f0.y * W_edge[128+ko+1]
            + f0.z * W_edge[128+ko+2]   + f0.w * W_edge[128+ko+3]
            + f1.x * W_edge[128+ko+4]   + f1.y * W_edge[128+ko+5]
            + f1.z * W_edge[128+ko+6]   + f1.w * W_edge[128+ko+7];
        short8 a;
        a[0] = (short)f2b(f0.x); a[1] = (short)f2b(f0.y);
        a[2] = (short)f2b(f0.z); a[3] = (short)f2b(f0.w);
        a[4] = (short)f2b(f1.x); a[5] = (short)f2b(f1.y);
        a[6] = (short)f2b(f1.z); a[7] = (short)f2b(f1.w);
        A[kf] = a;
        if (aok) *(short8*)(nf16 + (size_t)arow * 128 + ko) = a;
    }
    pd += __shfl_xor(pd, 16); pd += __shfl_xor(pd, 32);
    ps += __shfl_xor(ps, 16); ps += __shfl_xor(ps, 32);
    if (hi == 0 && aok) { s_d[arow] = pd; s_s[arow] = ps; }

    __syncthreads();                           // LDS weights ready

    int crow0 = r0 + hi * 4;
#pragma unroll 1
    for (int nc = 0; nc < 8; ++nc) {
        f32x4 acc = {0.f, 0.f, 0.f, 0.f};
        int col = nc * 16 + am;
#pragma unroll
        for (int kf = 0; kf < 4; ++kf) {
            short8 B = *(const short8*)(plds + col * 128 + (((kf * 4 + hi) ^ am) * 8));
            acc = __builtin_amdgcn_mfma_f32_16x16x32_bf16(A[kf], B, acc, 0, 0, 0);
        }
        float b = b_proj[col];
#pragma unroll
        for (int r = 0; r < 4; ++r) {
            int grow = crow0 + r;
            if (grow < N) hv16[(size_t)grow * 128 + col] = f2b(acc[r] + b);
        }
    }
}

// ---- pass 1 over edges: XCD-binned in-degree counts ----------------------
__global__ void k_edge(
    const int* __restrict__ dst, int* __restrict__ count, int N, int E)
{
    int e = blockIdx.x * blockDim.x + threadIdx.x;
    if (e >= E) return;
    int x = blockIdx.x & 7;                    // bin == XCD if round-robin
    atomicAdd(&count[x * N + dst[e]], 1);
}

// ---- 3-level scan for binned CSR offsets (M = 8N elements) ---------------
__global__ __launch_bounds__(256) void k_scan_local(
    const int* __restrict__ count, int* __restrict__ lex,
    int* __restrict__ bsum, int M)
{
    __shared__ int sdata[256];
    int tid = threadIdx.x;
    int i = blockIdx.x * 256 + tid;
    int v = (i < M) ? count[i] : 0;
    int incl = v;
    sdata[tid] = incl; __syncthreads();
#pragma unroll
    for (int off = 1; off < 256; off <<= 1) {
        int add = (tid >= off) ? sdata[tid - off] : 0;
        __syncthreads();
        incl += add;
        sdata[tid] = incl;
        __syncthreads();
    }
    if (i < M) lex[i] = incl - v;
    if (tid == 255) bsum[blockIdx.x] = incl;
}

__global__ __launch_bounds__(256) void k_scan_blocks(int* __restrict__ bsum, int nb)
{
    __shared__ int sdata[256];
    __shared__ int carry_s;
    int tid = threadIdx.x;
    if (tid == 0) carry_s = 0;
    __syncthreads();
    for (int base = 0; base < nb; base += 256) {
        int i = base + tid;
        int v = (i < nb) ? bsum[i] : 0;
        int incl = v;
        sdata[tid] = incl; __syncthreads();
#pragma unroll
        for (int off = 1; off < 256; off <<= 1) {
            int add = (tid >= off) ? sdata[tid - off] : 0;
            __syncthreads();
            incl += add;
            sdata[tid] = incl;
            __syncthreads();
        }
        int carry = carry_s;
        if (i < nb) bsum[i] = carry + incl - v;   // exclusive
        int total = sdata[255];
        __syncthreads();
        if (tid == 0) carry_s = carry + total;
        __syncthreads();
    }
}

__global__ __launch_bounds__(256) void k_scan_apply(
    const int* __restrict__ lex, const int* __restrict__ bsum,
    int* __restrict__ row_start, int M)
{
    int i = blockIdx.x * 256 + threadIdx.x;
    if (i < M) row_start[i] = lex[i] + bsum[blockIdx.x];
}

// ---- pass 2: fill CSR (bin-local scatter; row_start becomes seg-end) -----
__global__ void k_fill(
    const int* __restrict__ src, const int* __restrict__ dst,
    int* __restrict__ row_start, uint_t* __restrict__ perm_u, int N, int E)
{
    int e = blockIdx.x * blockDim.x + threadIdx.x;
    if (e >= E) return;
    int x = blockIdx.x & 7;                    // must match k_edge's binning
    int pos = atomicAdd(&row_start[x * N + dst[e]], 1);
    perm_u[pos] = (uint_t)src[e];
}

// ---- aggregate: 8 segments/node, recompute softmax weights ---------------
__global__ __launch_bounds__(256) void k_agg2(
    const ushort_t* __restrict__ hv16, const int* __restrict__ row_end,
    const float* __restrict__ s_d, const float* __restrict__ s_s,
    const float* __restrict__ b_edge, const uint_t* __restrict__ perm_u,
    ushort_t* __restrict__ ctx16, int N)
{
    int w = threadIdx.x >> 6, lane = threadIdx.x & 63;
    int v = blockIdx.x * 4 + w;
    if (v >= N) return;
    float sdv = s_d[v] + b_edge[0];
    float num0 = 0.f, num1 = 0.f, one0 = 0.f, one1 = 0.f, den = 0.f;
    int tc = 0;
#pragma unroll 1
    for (int x = 0; x < 8; ++x) {
        int i = x * N + v;
        int end = row_end[i];
        int beg = (i == 0) ? 0 : row_end[i - 1];
        tc += end - beg;
        for (int chunk = beg; chunk < end; chunk += 64) {
            int m = min(64, end - chunk);
            int uu = 0; float ev = 0.f;
            if (lane < m) {
                uu = (int)perm_u[chunk + lane];
                float l = sdv + s_s[uu];
                l = l > 0.f ? l : 0.01f * l;
                ev = __expf(l);
            }
            for (int t = 0; t < m; ++t) {
                int u = __shfl(uu, t);
                float e = __shfl(ev, t);
                uint_t p = ((const uint_t*)(hv16 + (size_t)u * 128))[lane];
                float h0 = b2f((ushort_t)p);
                float h1 = b2f((ushort_t)(p >> 16));
                num0 = fmaf(h0, e, num0);
                num1 = fmaf(h1, e, num1);
                one0 += h0;
                one1 += h1;
                den += e;
            }
        }
    }
    float c0 = 0.f, c1 = 0.f;
    if (tc > 0) {
        float inv = 1.f / den;
        c0 = num0 * inv + one0;
        c1 = num1 * inv + one1;
    }
    c0 = c0 > 0.f ? c0 : expm1f(c0);
    c1 = c1 > 0.f ? c1 : expm1f(c1);
    uint_t packed = (uint_t)f2b(c0) | ((uint_t)f2b(c1) << 16);
    ((uint_t*)ctx16)[(size_t)v * 64 + lane] = packed;
}

// ---- fused GRU + relu + BN-stats (weights double-buffered in LDS) --------
__global__ __launch_bounds__(256, 2) void k_gru_mfma(
    const ushort_t* __restrict__ ctx16, const ushort_t* __restrict__ nf16,
    const ushort_t* __restrict__ Wih16, const ushort_t* __restrict__ Whh16,
    const float* __restrict__ b_ih, const float* __restrict__ b_hh,
    float* __restrict__ out, float* __restrict__ bn, int N)
{
    __shared__ ushort_t wlds[2 * 12288];   // 48 KB
    __shared__ float bnsum[2][4][128];     // 4 KB
    int w = threadIdx.x >> 6, lane = threadIdx.x & 63;
    int am = lane & 15, hi = lane >> 4, ak = hi * 8;
    int r0 = blockIdx.x * 128 + w * 32;

    for (int i = threadIdx.x; i < 1024; i += 256)
        ((float*)bnsum)[i] = 0.f;

    short8 st[6];
    auto stage_load = [&](int cb) {
#pragma unroll
        for (int i = 0; i < 6; ++i) {
            int ch = w * 6 + i, m = ch >> 2, g = ch & 3;
            int dloc = g * 4 + hi;
            int wrow = (m >> 1) * 128 + cb * 16 + dloc;
            const ushort_t* sb = (m & 1) ? Whh16 : Wih16;
            st[i] = *(const short8*)(sb + (size_t)wrow * 128 + am * 8);
        }
    };
    auto stage_write = [&](int buf) {
#pragma unroll
        for (int i = 0; i < 6; ++i) {
            int ch = w * 6 + i, m = ch >> 2, g = ch & 3;
            int dloc = g * 4 + hi;
            *(short8*)(wlds + buf * 12288 + m * 2048 + dloc * 128 + ((am ^ dloc) * 8)) = st[i];
        }
    };

    stage_load(0);
    stage_write(0);

    short8 Ac[2][4], An[2][4];
#pragma unroll
    for (int rf = 0; rf < 2; ++rf) {
        int arow = r0 + rf * 16 + am;
        bool aok = arow < N;
        short8 z = {0,0,0,0,0,0,0,0};
#pragma unroll
        for (int kf = 0; kf < 4; ++kf) {
            size_t off = (size_t)arow * 128 + kf * 32 + ak;
            Ac[rf][kf] = aok ? *(const short8*)(ctx16 + off) : z;
            An[rf][kf] = aok ? *(const short8*)(nf16 + off) : z;
        }
    }

#pragma unroll 1
    for (int c = 0; c < 8; ++c) {
        __syncthreads();                       // buf[c&1] fully written
        int buf = c & 1;
        if (c < 7) stage_load(c + 1);

        int d = c * 16 + am;
        f32x4 racc[2], zacc[2], iacc[2], hacc[2];
#pragma unroll
        for (int rf = 0; rf < 2; ++rf) {
            racc[rf] = (f32x4){0.f,0.f,0.f,0.f};
            zacc[rf] = (f32x4){0.f,0.f,0.f,0.f};
            iacc[rf] = (f32x4){0.f,0.f,0.f,0.f};
            hacc[rf] = (f32x4){0.f,0.f,0.f,0.f};
        }
#pragma unroll
        for (int kf = 0; kf < 4; ++kf) {
            const ushort_t* bp = wlds + buf * 12288 + am * 128
                               + (((kf * 4 + hi) ^ am) * 8);
            short8 Br = *(const short8*)(bp + 0 * 2048);
            short8 Cr = *(const short8*)(bp + 1 * 2048);
            short8 Bz = *(const short8*)(bp + 2 * 2048);
            short8 Cz = *(const short8*)(bp + 3 * 2048);
            short8 Bi = *(const short8*)(bp + 4 * 2048);
            short8 Ch = *(const short8*)(bp + 5 * 2048);
#pragma unroll
            for (int rf = 0; rf < 2; ++rf) {
                racc[rf] = __builtin_amdgcn_mfma_f32_16x16x32_bf16(Ac[rf][kf], Br, racc[rf], 0, 0, 0);
                racc[rf] = __builtin_amdgcn_mfma_f32_16x16x32_bf16(An[rf][kf], Cr, racc[rf], 0, 0, 0);
                zacc[rf] = __builtin_amdgcn_mfma_f32_16x16x32_bf16(Ac[rf][kf], Bz, zacc[rf], 0, 0, 0);
                zacc[rf] = __builtin_amdgcn_mfma_f32_16x16x32_bf16(An[rf][kf], Cz, zacc[rf], 0, 0, 0);
                iacc[rf] = __builtin_amdgcn_mfma_f32_16x16x32_bf16(Ac[rf][kf], Bi, iacc[rf], 0, 0, 0);
                hacc[rf] = __builtin_amdgcn_mfma_f32_16x16x32_bf16(An[rf][kf], Ch, hacc[rf], 0, 0, 0);
            }
        }
        float br = b_ih[d] + b_hh[d];
        float bz = b_ih[128 + d] + b_hh[128 + d];
        float bi = b_ih[256 + d];
        float bh = b_hh[256 + d];
        float cs = 0.f, cs2 = 0.f;
#pragma unroll
        for (int rf = 0; rf < 2; ++rf) {
            int crow0 = r0 + rf * 16 + hi * 4;
#pragma unroll
            for (int r = 0; r < 4; ++r) {
                int grow = crow0 + r;
                if (grow >= N) continue;
                float rv = sigm(racc[rf][r] + br);
                float zv = sigm(zacc[rf][r] + bz);
                float nv = tanh_(iacc[rf][r] + bi + rv * (hacc[rf][r] + bh));
                float hp = b2f(nf16[(size_t)grow * 128 + d]);
                float h = (1.f - zv) * nv + zv * hp;
                h = fmaxf(h, 0.f);
                out[(size_t)grow * 128 + d] = h;
                cs += h;
                cs2 = fmaf(h, h, cs2);
            }
        }
        cs  += __shfl_xor(cs, 16);  cs  += __shfl_xor(cs, 32);
        cs2 += __shfl_xor(cs2, 16); cs2 += __shfl_xor(cs2, 32);
        if (hi == 0) {
            bnsum[0][w][d] += cs;
            bnsum[1][w][d] += cs2;
        }
        __syncthreads();                       // everyone done reading buf
        if (c < 7) stage_write(buf ^ 1);
    }
    __syncthreads();
    int t = threadIdx.x;
    if (t < 128) {
        float s = bnsum[0][0][t] + bnsum[0][1][t] + bnsum[0][2][t] + bnsum[0][3][t];
        atomicAdd(&bn[t], s);
    } else {
        int d2 = t - 128;
        float s2 = bnsum[1][0][d2] + bnsum[1][1][d2] + bnsum[1][2][d2] + bnsum[1][3][d2];
        atomicAdd(&bn[128 + d2], s2);
    }
}

// ---- BatchNorm normalize -------------------------------------------------
__global__ __launch_bounds__(256) void k_bnnorm(
    float* __restrict__ out, const float* __restrict__ bn,
    const float* __restrict__ gamma, const float* __restrict__ beta, int N)
{
    int idx = blockIdx.x * 256 + threadIdx.x;
    int total = N * 128;
    if (idx >= total) return;
    int d = idx & 127;
    float invN = 1.f / (float)N;
    float mean = bn[d] * invN;
    float var = bn[128 + d] * invN - mean * mean;
    float inv_std = rsqrtf(var + 1e-5f);
    float x = out[idx];
    out[idx] = (x - mean) * inv_std * gamma[d] + beta[d];
}

// ---- host launcher -------------------------------------------------------
extern "C" void kernel_launch(void* const* d_in, const int* in_sizes, int n_in,
                              void* d_out, int out_size, void* d_ws, size_t ws_size,
                              hipStream_t stream)
{
    const float* nf     = (const float*)d_in[0];
    const int*   src    = (const int*)  d_in[1];
    const int*   dst    = (const int*)  d_in[2];
    const float* W_edge = (const float*)d_in[3];
    const float* b_edge = (const float*)d_in[4];
    const float* W_proj = (const float*)d_in[5];
    const float* b_proj = (const float*)d_in[6];
    const float* W_ih   = (const float*)d_in[7];
    const float* W_hh   = (const float*)d_in[8];
    const float* b_ih   = (const float*)d_in[9];
    const float* b_hh   = (const float*)d_in[10];
    const float* bn_g   = (const float*)d_in[11];
    const float* bn_b   = (const float*)d_in[12];

    const int N = in_sizes[0] / D;   // 50000
    const int E = in_sizes[1];       // 600000
    const int M = 8 * N;             // binned count/offset array length

    float* ws = (float*)d_ws;
    float* s_d       = ws;                                  // N
    float* s_s       = ws + (size_t)N;                      // N
    int*   count     = (int*)(ws + (size_t)2 * N);          // 8N
    int*   lex       = (int*)(ws + (size_t)10 * N);         // 8N
    int*   row_start = (int*)(ws + (size_t)18 * N);         // 8N (seg-end after fill)
    uint_t* perm_u   = (uint_t*)(ws + (size_t)26 * N);      // E
    float* bn        = ws + (size_t)26 * N + (size_t)E;     // 256
    int*   bsum      = (int*)(bn + 256);                    // 2048
    ushort_t* nf16   = (ushort_t*)(bn + 256 + 2048);
    ushort_t* hv16   = nf16 + (size_t)N * 128;
    ushort_t* ctx16  = hv16 + (size_t)N * 128;
    ushort_t* Wih16  = ctx16 + (size_t)N * 128;
    ushort_t* Whh16  = Wih16 + 384 * 128;
    ushort_t* WpT16  = Whh16 + 384 * 128;

    float* outp = (float*)d_out;

    hipMemsetAsync(count, 0, (size_t)M * sizeof(int), stream);
    hipMemsetAsync(bn, 0, 256 * sizeof(float), stream);

    int nb_scan = (M + 255) / 256;   // 1563 (<= 2048 bsum slots)

    k_prep_w<<<(114688 + 255) / 256, 256, 0, stream>>>(W_ih, W_hh, W_proj,
                                                       Wih16, Whh16, WpT16);
    k_hv_fused<<<(N + 63) / 64, 256, 0, stream>>>(nf, WpT16, b_proj, W_edge,
                                                  nf16, hv16, s_d, s_s, N);
    k_edge<<<(E + 255) / 256, 256, 0, stream>>>(dst, count, N, E);
    k_scan_local<<<nb_scan, 256, 0, stream>>>(count, lex, bsum, M);
    k_scan_blocks<<<1, 256, 0, stream>>>(bsum, nb_scan);
    k_scan_apply<<<nb_scan, 256, 0, stream>>>(lex, bsum, row_start, M);
    k_fill<<<(E + 255) / 256, 256, 0, stream>>>(src, dst, row_start, perm_u, N, E);
    k_agg2<<<(N + 3) / 4, 256, 0, stream>>>(hv16, row_start, s_d, s_s,
                                            b_edge, perm_u, ctx16, N);
    k_gru_mfma<<<(N + 127) / 128, 256, 0, stream>>>(ctx16, nf16, Wih16, Whh16,
                                                    b_ih, b_hh, outp, bn, N);
    k_bnnorm<<<(N * D + 255) / 256, 256, 0, stream>>>(outp, bn, bn_g, bn_b, N);
}

// Round 8
// 235.196 us; speedup vs baseline: 1.0009x; 1.0009x over previous
//
#include <hip/hip_runtime.h>
#include <math.h>

constexpr int D = 128;

typedef __attribute__((ext_vector_type(8))) short short8;
typedef __attribute__((ext_vector_type(4))) float f32x4;
typedef unsigned short ushort_t;
typedef unsigned int uint_t;

__device__ inline ushort_t f2b(float x) {          // fp32 -> bf16 RNE
    uint_t u = __float_as_uint(x);
    uint_t r = u + 0x7fffu + ((u >> 16) & 1u);
    return (ushort_t)(r >> 16);
}
__device__ inline float b2f(ushort_t b) { return __uint_as_float(((uint_t)b) << 16); }

__device__ inline float sigm(float x) { return 1.f / (1.f + __expf(-x)); }
__device__ inline float tanh_(float x) {
    float t = __expf(-2.f * fabsf(x));
    float y = (1.f - t) / (1.f + t);
    return x >= 0.f ? y : -y;
}

// ---- convert weights to bf16 ---------------------------------------------
__global__ __launch_bounds__(256) void k_prep_w(
    const float* __restrict__ W_ih, const float* __restrict__ W_hh,
    const float* __restrict__ W_proj,
    ushort_t* __restrict__ Wih16, ushort_t* __restrict__ Whh16,
    ushort_t* __restrict__ WpT16)
{
    int idx = blockIdx.x * 256 + threadIdx.x;
    if (idx < 49152) {
        Wih16[idx] = f2b(W_ih[idx]);
    } else if (idx < 98304) {
        int i = idx - 49152;
        Whh16[i] = f2b(W_hh[i]);
    } else if (idx < 114688) {
        int t = idx - 98304;           // WpT[j][k] = W_proj[k][j]
        int j = t >> 7, k = t & 127;
        WpT16[t] = f2b(W_proj[k * 128 + j]);
    }
}

// ---- fused: nf->bf16, edge scores, hv16 = bf16(nf@WpT+b) (MFMA) ----------
__global__ __launch_bounds__(256, 2) void k_hv_fused(
    const float* __restrict__ nf, const ushort_t* __restrict__ WpT16,
    const float* __restrict__ b_proj, const float* __restrict__ W_edge,
    ushort_t* __restrict__ nf16, ushort_t* __restrict__ hv16,
    float* __restrict__ s_d, float* __restrict__ s_s, int N)
{
    __shared__ ushort_t plds[16384];           // 128 x 128 bf16 = 32 KB
    int w = threadIdx.x >> 6, lane = threadIdx.x & 63;
    int am = lane & 15, hi = lane >> 4, ak = hi * 8;

    // stage WpT into LDS once (swizzled: slot ^= row&15)
#pragma unroll
    for (int i = 0; i < 8; ++i) {
        int dl = (w * 8 + i) * 4 + hi;         // 0..127
        short8 v = *(const short8*)(WpT16 + (size_t)dl * 128 + am * 8);
        *(short8*)(plds + dl * 128 + ((am ^ (dl & 15)) * 8)) = v;
    }

    int r0 = blockIdx.x * 64 + w * 16;
    int arow = r0 + am;
    bool aok = arow < N;
    short8 A[4];
    float pd = 0.f, ps = 0.f;
#pragma unroll
    for (int kf = 0; kf < 4; ++kf) {
        int ko = kf * 32 + ak;
        float4 f0 = {0,0,0,0}, f1 = {0,0,0,0};
        if (aok) {
            f0 = *(const float4*)(nf + (size_t)arow * 128 + ko);
            f1 = *(const float4*)(nf + (size_t)arow * 128 + ko + 4);
        }
        pd += f0.x * W_edge[ko]     + f0.y * W_edge[ko + 1]
            + f0.z * W_edge[ko + 2] + f0.w * W_edge[ko + 3]
            + f1.x * W_edge[ko + 4] + f1.y * W_edge[ko + 5]
            + f1.z * W_edge[ko + 6] + f1.w * W_edge[ko + 7];
        ps += f0.x * W_edge[128+ko]     + f0.y * W_edge[128+ko+1]
            + f0.z * W_edge[128+ko+2]   + f0.w * W_edge[128+ko+3]
            + f1.x * W_edge[128+ko+4]   + f1.y * W_edge[128+ko+5]
            + f1.z * W_edge[128+ko+6]   + f1.w * W_edge[128+ko+7];
        short8 a;
        a[0] = (short)f2b(f0.x); a[1] = (short)f2b(f0.y);
        a[2] = (short)f2b(f0.z); a[3] = (short)f2b(f0.w);
        a[4] = (short)f2b(f1.x); a[5] = (short)f2b(f1.y);
        a[6] = (short)f2b(f1.z); a[7] = (short)f2b(f1.w);
        A[kf] = a;
        if (aok) *(short8*)(nf16 + (size_t)arow * 128 + ko) = a;
    }
    pd += __shfl_xor(pd, 16); pd += __shfl_xor(pd, 32);
    ps += __shfl_xor(ps, 16); ps += __shfl_xor(ps, 32);
    if (hi == 0 && aok) { s_d[arow] = pd; s_s[arow] = ps; }

    __syncthreads();                           // LDS weights ready

    int crow0 = r0 + hi * 4;
#pragma unroll 1
    for (int nc = 0; nc < 8; ++nc) {
        f32x4 acc = {0.f, 0.f, 0.f, 0.f};
        int col = nc * 16 + am;
#pragma unroll
        for (int kf = 0; kf < 4; ++kf) {
            short8 B = *(const short8*)(plds + col * 128 + (((kf * 4 + hi) ^ am) * 8));
            acc = __builtin_amdgcn_mfma_f32_16x16x32_bf16(A[kf], B, acc, 0, 0, 0);
        }
        float b = b_proj[col];
#pragma unroll
        for (int r = 0; r < 4; ++r) {
            int grow = crow0 + r;
            if (grow < N) hv16[(size_t)grow * 128 + col] = f2b(acc[r] + b);
        }
    }
}

// ---- pass 1 over edges: XCD-binned in-degree counts ----------------------
__global__ void k_edge(
    const int* __restrict__ dst, int* __restrict__ count, int N, int E)
{
    int e = blockIdx.x * blockDim.x + threadIdx.x;
    if (e >= E) return;
    int x = blockIdx.x & 7;                    // bin == XCD if round-robin
    atomicAdd(&count[x * N + dst[e]], 1);
}

// ---- 3-level scan for binned CSR offsets (M = 8N elements) ---------------
__global__ __launch_bounds__(256) void k_scan_local(
    const int* __restrict__ count, int* __restrict__ lex,
    int* __restrict__ bsum, int M)
{
    __shared__ int sdata[256];
    int tid = threadIdx.x;
    int i = blockIdx.x * 256 + tid;
    int v = (i < M) ? count[i] : 0;
    int incl = v;
    sdata[tid] = incl; __syncthreads();
#pragma unroll
    for (int off = 1; off < 256; off <<= 1) {
        int add = (tid >= off) ? sdata[tid - off] : 0;
        __syncthreads();
        incl += add;
        sdata[tid] = incl;
        __syncthreads();
    }
    if (i < M) lex[i] = incl - v;
    if (tid == 255) bsum[blockIdx.x] = incl;
}

__global__ __launch_bounds__(256) void k_scan_blocks(int* __restrict__ bsum, int nb)
{
    __shared__ int sdata[256];
    __shared__ int carry_s;
    int tid = threadIdx.x;
    if (tid == 0) carry_s = 0;
    __syncthreads();
    for (int base = 0; base < nb; base += 256) {
        int i = base + tid;
        int v = (i < nb) ? bsum[i] : 0;
        int incl = v;
        sdata[tid] = incl; __syncthreads();
#pragma unroll
        for (int off = 1; off < 256; off <<= 1) {
            int add = (tid >= off) ? sdata[tid - off] : 0;
            __syncthreads();
            incl += add;
            sdata[tid] = incl;
            __syncthreads();
        }
        int carry = carry_s;
        if (i < nb) bsum[i] = carry + incl - v;   // exclusive
        int total = sdata[255];
        __syncthreads();
        if (tid == 0) carry_s = carry + total;
        __syncthreads();
    }
}

__global__ __launch_bounds__(256) void k_scan_apply(
    const int* __restrict__ lex, const int* __restrict__ bsum,
    int* __restrict__ row_off, int M)
{
    int i = blockIdx.x * 256 + threadIdx.x;
    if (i < M) row_off[i] = lex[i] + bsum[blockIdx.x];
}

// ---- pass 2: fill CSR (XCD-local 8B records) + den atomics ---------------
__global__ void k_fill(
    const int* __restrict__ src, const int* __restrict__ dst,
    const float* __restrict__ s_d, const float* __restrict__ s_s,
    const float* __restrict__ b_edge, float* __restrict__ den,
    int* __restrict__ row_off, uint2* __restrict__ edge_rec, int N, int E)
{
    int e = blockIdx.x * blockDim.x + threadIdx.x;
    if (e >= E) return;
    int s = src[e], t = dst[e];
    float l = s_d[t] + s_s[s] + b_edge[0];
    l = l > 0.f ? l : 0.01f * l;
    float ev = __expf(l);
    atomicAdd(&den[t], ev);
    int x = blockIdx.x & 7;                    // must match k_edge's binning
    int pos = atomicAdd(&row_off[x * N + t], 1);
    uint2 rec;
    rec.x = (uint_t)s;
    rec.y = __float_as_uint(ev);
    edge_rec[pos] = rec;
}

// ---- aggregate: LDS-staged edge list, 4-deep pipelined row gathers -------
__global__ __launch_bounds__(256) void k_agg3(
    const ushort_t* __restrict__ hv16, const int* __restrict__ row_end,
    const int* __restrict__ count, const float* __restrict__ den,
    const uint2* __restrict__ edge_rec, ushort_t* __restrict__ ctx16, int N)
{
    __shared__ uint2 elds[4][128];             // 4 nodes x <=128 edges = 4 KB
    int w = threadIdx.x >> 6, lane = threadIdx.x & 63;
    int v = blockIdx.x * 4 + w;
    bool vok = v < N;

    int begs[8], cnts[8];
    int total = 0;
    if (vok) {
#pragma unroll
        for (int x = 0; x < 8; ++x) {
            int i = x * N + v;
            int end = row_end[i];              // wave-uniform scalar loads
            int cnt = count[i];
            begs[x] = end - cnt;
            cnts[x] = cnt;
        }
#pragma unroll
        for (int x = 0; x < 8; ++x) {
            for (int c = lane; c < cnts[x]; c += 64) {
                int idx = total + c;
                if (idx < 128) elds[w][idx] = edge_rec[begs[x] + c];
            }
            total += cnts[x];
        }
    }
    float inv = 0.f;
    if (vok) {
        float dv = den[v];
        inv = dv > 0.f ? 1.f / dv : 0.f;
    }

    float c0 = 0.f, c1 = 0.f;
    int cap = min(total, 128);
    for (int t0 = 0; t0 < cap; t0 += 4) {
        uint_t p[4];
        float wt[4];
#pragma unroll
        for (int k = 0; k < 4; ++k) {
            int tt = t0 + k;
            uint2 er = elds[w][tt < cap ? tt : 0];
            wt[k] = (tt < cap) ? fmaf(__uint_as_float(er.y), inv, 1.0f) : 0.f;
            p[k] = ((const uint_t*)(hv16 + ((size_t)er.x << 7)))[lane];
        }
#pragma unroll
        for (int k = 0; k < 4; ++k) {
            c0 = fmaf(b2f((ushort_t)p[k]), wt[k], c0);
            c1 = fmaf(b2f((ushort_t)(p[k] >> 16)), wt[k], c1);
        }
    }
    if (total > 128) {                         // ~never taken (deg>128)
        int flat = 0;
#pragma unroll 1
        for (int x = 0; x < 8; ++x) {
            for (int c = 0; c < cnts[x]; ++c) {
                if (flat + c >= 128) {
                    uint2 er = edge_rec[begs[x] + c];
                    float wt2 = fmaf(__uint_as_float(er.y), inv, 1.0f);
                    uint_t p2 = ((const uint_t*)(hv16 + ((size_t)er.x << 7)))[lane];
                    c0 = fmaf(b2f((ushort_t)p2), wt2, c0);
                    c1 = fmaf(b2f((ushort_t)(p2 >> 16)), wt2, c1);
                }
            }
            flat += cnts[x];
        }
    }
    if (!vok) return;
    c0 = c0 > 0.f ? c0 : expm1f(c0);
    c1 = c1 > 0.f ? c1 : expm1f(c1);
    uint_t packed = (uint_t)f2b(c0) | ((uint_t)f2b(c1) << 16);
    ((uint_t*)ctx16)[(size_t)v * 64 + lane] = packed;
}

// ---- fused GRU + relu + BN-stats (weights double-buffered in LDS) --------
__global__ __launch_bounds__(256, 2) void k_gru_mfma(
    const ushort_t* __restrict__ ctx16, const ushort_t* __restrict__ nf16,
    const ushort_t* __restrict__ Wih16, const ushort_t* __restrict__ Whh16,
    const float* __restrict__ b_ih, const float* __restrict__ b_hh,
    float* __restrict__ out, float* __restrict__ bn, int N)
{
    __shared__ ushort_t wlds[2 * 12288];   // 48 KB
    __shared__ float bnsum[2][4][128];     // 4 KB
    int w = threadIdx.x >> 6, lane = threadIdx.x & 63;
    int am = lane & 15, hi = lane >> 4, ak = hi * 8;
    int r0 = blockIdx.x * 128 + w * 32;

    for (int i = threadIdx.x; i < 1024; i += 256)
        ((float*)bnsum)[i] = 0.f;

    short8 st[6];
    auto stage_load = [&](int cb) {
#pragma unroll
        for (int i = 0; i < 6; ++i) {
            int ch = w * 6 + i, m = ch >> 2, g = ch & 3;
            int dloc = g * 4 + hi;
            int wrow = (m >> 1) * 128 + cb * 16 + dloc;
            const ushort_t* sb = (m & 1) ? Whh16 : Wih16;
            st[i] = *(const short8*)(sb + (size_t)wrow * 128 + am * 8);
        }
    };
    auto stage_write = [&](int buf) {
#pragma unroll
        for (int i = 0; i < 6; ++i) {
            int ch = w * 6 + i, m = ch >> 2, g = ch & 3;
            int dloc = g * 4 + hi;
            *(short8*)(wlds + buf * 12288 + m * 2048 + dloc * 128 + ((am ^ dloc) * 8)) = st[i];
        }
    };

    stage_load(0);
    stage_write(0);

    short8 Ac[2][4], An[2][4];
#pragma unroll
    for (int rf = 0; rf < 2; ++rf) {
        int arow = r0 + rf * 16 + am;
        bool aok = arow < N;
        short8 z = {0,0,0,0,0,0,0,0};
#pragma unroll
        for (int kf = 0; kf < 4; ++kf) {
            size_t off = (size_t)arow * 128 + kf * 32 + ak;
            Ac[rf][kf] = aok ? *(const short8*)(ctx16 + off) : z;
            An[rf][kf] = aok ? *(const short8*)(nf16 + off) : z;
        }
    }

#pragma unroll 1
    for (int c = 0; c < 8; ++c) {
        __syncthreads();                       // buf[c&1] fully written
        int buf = c & 1;
        if (c < 7) stage_load(c + 1);

        int d = c * 16 + am;
        f32x4 racc[2], zacc[2], iacc[2], hacc[2];
#pragma unroll
        for (int rf = 0; rf < 2; ++rf) {
            racc[rf] = (f32x4){0.f,0.f,0.f,0.f};
            zacc[rf] = (f32x4){0.f,0.f,0.f,0.f};
            iacc[rf] = (f32x4){0.f,0.f,0.f,0.f};
            hacc[rf] = (f32x4){0.f,0.f,0.f,0.f};
        }
#pragma unroll
        for (int kf = 0; kf < 4; ++kf) {
            const ushort_t* bp = wlds + buf * 12288 + am * 128
                               + (((kf * 4 + hi) ^ am) * 8);
            short8 Br = *(const short8*)(bp + 0 * 2048);
            short8 Cr = *(const short8*)(bp + 1 * 2048);
            short8 Bz = *(const short8*)(bp + 2 * 2048);
            short8 Cz = *(const short8*)(bp + 3 * 2048);
            short8 Bi = *(const short8*)(bp + 4 * 2048);
            short8 Ch = *(const short8*)(bp + 5 * 2048);
#pragma unroll
            for (int rf = 0; rf < 2; ++rf) {
                racc[rf] = __builtin_amdgcn_mfma_f32_16x16x32_bf16(Ac[rf][kf], Br, racc[rf], 0, 0, 0);
                racc[rf] = __builtin_amdgcn_mfma_f32_16x16x32_bf16(An[rf][kf], Cr, racc[rf], 0, 0, 0);
                zacc[rf] = __builtin_amdgcn_mfma_f32_16x16x32_bf16(Ac[rf][kf], Bz, zacc[rf], 0, 0, 0);
                zacc[rf] = __builtin_amdgcn_mfma_f32_16x16x32_bf16(An[rf][kf], Cz, zacc[rf], 0, 0, 0);
                iacc[rf] = __builtin_amdgcn_mfma_f32_16x16x32_bf16(Ac[rf][kf], Bi, iacc[rf], 0, 0, 0);
                hacc[rf] = __builtin_amdgcn_mfma_f32_16x16x32_bf16(An[rf][kf], Ch, hacc[rf], 0, 0, 0);
            }
        }
        float br = b_ih[d] + b_hh[d];
        float bz = b_ih[128 + d] + b_hh[128 + d];
        float bi = b_ih[256 + d];
        float bh = b_hh[256 + d];
        float cs = 0.f, cs2 = 0.f;
#pragma unroll
        for (int rf = 0; rf < 2; ++rf) {
            int crow0 = r0 + rf * 16 + hi * 4;
#pragma unroll
            for (int r = 0; r < 4; ++r) {
                int grow = crow0 + r;
                if (grow >= N) continue;
                float rv = sigm(racc[rf][r] + br);
                float zv = sigm(zacc[rf][r] + bz);
                float nv = tanh_(iacc[rf][r] + bi + rv * (hacc[rf][r] + bh));
                float hp = b2f(nf16[(size_t)grow * 128 + d]);
                float h = (1.f - zv) * nv + zv * hp;
                h = fmaxf(h, 0.f);
                out[(size_t)grow * 128 + d] = h;
                cs += h;
                cs2 = fmaf(h, h, cs2);
            }
        }
        cs  += __shfl_xor(cs, 16);  cs  += __shfl_xor(cs, 32);
        cs2 += __shfl_xor(cs2, 16); cs2 += __shfl_xor(cs2, 32);
        if (hi == 0) {
            bnsum[0][w][d] += cs;
            bnsum[1][w][d] += cs2;
        }
        __syncthreads();                       // everyone done reading buf
        if (c < 7) stage_write(buf ^ 1);
    }
    __syncthreads();
    int t = threadIdx.x;
    if (t < 128) {
        float s = bnsum[0][0][t] + bnsum[0][1][t] + bnsum[0][2][t] + bnsum[0][3][t];
        atomicAdd(&bn[t], s);
    } else {
        int d2 = t - 128;
        float s2 = bnsum[1][0][d2] + bnsum[1][1][d2] + bnsum[1][2][d2] + bnsum[1][3][d2];
        atomicAdd(&bn[128 + d2], s2);
    }
}

// ---- BatchNorm normalize -------------------------------------------------
__global__ __launch_bounds__(256) void k_bnnorm(
    float* __restrict__ out, const float* __restrict__ bn,
    const float* __restrict__ gamma, const float* __restrict__ beta, int N)
{
    int idx = blockIdx.x * 256 + threadIdx.x;
    int total = N * 128;
    if (idx >= total) return;
    int d = idx & 127;
    float invN = 1.f / (float)N;
    float mean = bn[d] * invN;
    float var = bn[128 + d] * invN - mean * mean;
    float inv_std = rsqrtf(var + 1e-5f);
    float x = out[idx];
    out[idx] = (x - mean) * inv_std * gamma[d] + beta[d];
}

// ---- host launcher -------------------------------------------------------
extern "C" void kernel_launch(void* const* d_in, const int* in_sizes, int n_in,
                              void* d_out, int out_size, void* d_ws, size_t ws_size,
                              hipStream_t stream)
{
    const float* nf     = (const float*)d_in[0];
    const int*   src    = (const int*)  d_in[1];
    const int*   dst    = (const int*)  d_in[2];
    const float* W_edge = (const float*)d_in[3];
    const float* b_edge = (const float*)d_in[4];
    const float* W_proj = (const float*)d_in[5];
    const float* b_proj = (const float*)d_in[6];
    const float* W_ih   = (const float*)d_in[7];
    const float* W_hh   = (const float*)d_in[8];
    const float* b_ih   = (const float*)d_in[9];
    const float* b_hh   = (const float*)d_in[10];
    const float* bn_g   = (const float*)d_in[11];
    const float* bn_b   = (const float*)d_in[12];

    const int N = in_sizes[0] / D;   // 50000
    const int E = in_sizes[1];       // 600000
    const int M = 8 * N;             // binned count/offset array length

    float* ws = (float*)d_ws;
    float* s_d       = ws;                                  // N
    float* s_s       = ws + (size_t)N;                      // N
    float* den       = ws + (size_t)2 * N;                  // N
    int*   count     = (int*)(ws + (size_t)3 * N);          // 8N
    int*   row_off   = (int*)(ws + (size_t)11 * N);         // 8N (seg-end after fill)
    int*   lex       = (int*)(ws + (size_t)19 * N);         // 8N
    float* bn        = ws + (size_t)27 * N;                 // 256
    int*   bsum      = (int*)(bn + 256);                    // 2048
    uint2* edge_rec  = (uint2*)(bsum + 2048);               // E * 8B
    ushort_t* nf16   = (ushort_t*)(edge_rec + (size_t)E);
    ushort_t* hv16   = nf16 + (size_t)N * 128;
    ushort_t* ctx16  = hv16 + (size_t)N * 128;
    ushort_t* Wih16  = ctx16 + (size_t)N * 128;
    ushort_t* Whh16  = Wih16 + 384 * 128;
    ushort_t* WpT16  = Whh16 + 384 * 128;

    float* outp = (float*)d_out;

    // den (N floats) + count (8N ints) are contiguous -> one memset
    hipMemsetAsync(den, 0, (size_t)9 * N * sizeof(float), stream);
    hipMemsetAsync(bn, 0, 256 * sizeof(float), stream);

    int nb_scan = (M + 255) / 256;   // 1563 (<= 2048 bsum slots)

    k_prep_w<<<(114688 + 255) / 256, 256, 0, stream>>>(W_ih, W_hh, W_proj,
                                                       Wih16, Whh16, WpT16);
    k_hv_fused<<<(N + 63) / 64, 256, 0, stream>>>(nf, WpT16, b_proj, W_edge,
                                                  nf16, hv16, s_d, s_s, N);
    k_edge<<<(E + 255) / 256, 256, 0, stream>>>(dst, count, N, E);
    k_scan_local<<<nb_scan, 256, 0, stream>>>(count, lex, bsum, M);
    k_scan_blocks<<<1, 256, 0, stream>>>(bsum, nb_scan);
    k_scan_apply<<<nb_scan, 256, 0, stream>>>(lex, bsum, row_off, M);
    k_fill<<<(E + 255) / 256, 256, 0, stream>>>(src, dst, s_d, s_s, b_edge,
                                                den, row_off, edge_rec, N, E);
    k_agg3<<<(N + 3) / 4, 256, 0, stream>>>(hv16, row_off, count, den,
                                            edge_rec, ctx16, N);
    k_gru_mfma<<<(N + 127) / 128, 256, 0, stream>>>(ctx16, nf16, Wih16, Whh16,
                                                    b_ih, b_hh, outp, bn, N);
    k_bnnorm<<<(N * D + 255) / 256, 256, 0, stream>>>(outp, bn, bn_g, bn_b, N);
}

// Round 9
// 227.529 us; speedup vs baseline: 1.0346x; 1.0337x over previous
//
#include <hip/hip_runtime.h>
#include <math.h>

constexpr int D = 128;

typedef __attribute__((ext_vector_type(8))) short short8;
typedef __attribute__((ext_vector_type(4))) float f32x4;
typedef unsigned short ushort_t;
typedef unsigned int uint_t;

__device__ inline ushort_t f2b(float x) {          // fp32 -> bf16 RNE
    uint_t u = __float_as_uint(x);
    uint_t r = u + 0x7fffu + ((u >> 16) & 1u);
    return (ushort_t)(r >> 16);
}
__device__ inline float b2f(ushort_t b) { return __uint_as_float(((uint_t)b) << 16); }

__device__ inline float sigm(float x) { return 1.f / (1.f + __expf(-x)); }
__device__ inline float tanh_(float x) {
    float t = __expf(-2.f * fabsf(x));
    float y = (1.f - t) / (1.f + t);
    return x >= 0.f ? y : -y;
}

// ---- convert weights to bf16 ---------------------------------------------
__global__ __launch_bounds__(256) void k_prep_w(
    const float* __restrict__ W_ih, const float* __restrict__ W_hh,
    const float* __restrict__ W_proj,
    ushort_t* __restrict__ Wih16, ushort_t* __restrict__ Whh16,
    ushort_t* __restrict__ WpT16)
{
    int idx = blockIdx.x * 256 + threadIdx.x;
    if (idx < 49152) {
        Wih16[idx] = f2b(W_ih[idx]);
    } else if (idx < 98304) {
        int i = idx - 49152;
        Whh16[i] = f2b(W_hh[i]);
    } else if (idx < 114688) {
        int t = idx - 98304;           // WpT[j][k] = W_proj[k][j]
        int j = t >> 7, k = t & 127;
        WpT16[t] = f2b(W_proj[k * 128 + j]);
    }
}

// ---- fused: nf->bf16, edge scores, hv16 = bf16(nf@WpT+b) (MFMA) ----------
__global__ __launch_bounds__(256, 2) void k_hv_fused(
    const float* __restrict__ nf, const ushort_t* __restrict__ WpT16,
    const float* __restrict__ b_proj, const float* __restrict__ W_edge,
    ushort_t* __restrict__ nf16, ushort_t* __restrict__ hv16,
    float* __restrict__ s_d, float* __restrict__ s_s, int N)
{
    __shared__ ushort_t plds[16384];           // 128 x 128 bf16 = 32 KB
    int w = threadIdx.x >> 6, lane = threadIdx.x & 63;
    int am = lane & 15, hi = lane >> 4, ak = hi * 8;

    // stage WpT into LDS once (swizzled: slot ^= row&15)
#pragma unroll
    for (int i = 0; i < 8; ++i) {
        int dl = (w * 8 + i) * 4 + hi;         // 0..127
        short8 v = *(const short8*)(WpT16 + (size_t)dl * 128 + am * 8);
        *(short8*)(plds + dl * 128 + ((am ^ (dl & 15)) * 8)) = v;
    }

    int r0 = blockIdx.x * 64 + w * 16;
    int arow = r0 + am;
    bool aok = arow < N;
    short8 A[4];
    float pd = 0.f, ps = 0.f;
#pragma unroll
    for (int kf = 0; kf < 4; ++kf) {
        int ko = kf * 32 + ak;
        float4 f0 = {0,0,0,0}, f1 = {0,0,0,0};
        if (aok) {
            f0 = *(const float4*)(nf + (size_t)arow * 128 + ko);
            f1 = *(const float4*)(nf + (size_t)arow * 128 + ko + 4);
        }
        pd += f0.x * W_edge[ko]     + f0.y * W_edge[ko + 1]
            + f0.z * W_edge[ko + 2] + f0.w * W_edge[ko + 3]
            + f1.x * W_edge[ko + 4] + f1.y * W_edge[ko + 5]
            + f1.z * W_edge[ko + 6] + f1.w * W_edge[ko + 7];
        ps += f0.x * W_edge[128+ko]     + f0.y * W_edge[128+ko+1]
            + f0.z * W_edge[128+ko+2]   + f0.w * W_edge[128+ko+3]
            + f1.x * W_edge[128+ko+4]   + f1.y * W_edge[128+ko+5]
            + f1.z * W_edge[128+ko+6]   + f1.w * W_edge[128+ko+7];
        short8 a;
        a[0] = (short)f2b(f0.x); a[1] = (short)f2b(f0.y);
        a[2] = (short)f2b(f0.z); a[3] = (short)f2b(f0.w);
        a[4] = (short)f2b(f1.x); a[5] = (short)f2b(f1.y);
        a[6] = (short)f2b(f1.z); a[7] = (short)f2b(f1.w);
        A[kf] = a;
        if (aok) *(short8*)(nf16 + (size_t)arow * 128 + ko) = a;
    }
    pd += __shfl_xor(pd, 16); pd += __shfl_xor(pd, 32);
    ps += __shfl_xor(ps, 16); ps += __shfl_xor(ps, 32);
    if (hi == 0 && aok) { s_d[arow] = pd; s_s[arow] = ps; }

    __syncthreads();                           // LDS weights ready

    int crow0 = r0 + hi * 4;
#pragma unroll 1
    for (int nc = 0; nc < 8; ++nc) {
        f32x4 acc = {0.f, 0.f, 0.f, 0.f};
        int col = nc * 16 + am;
#pragma unroll
        for (int kf = 0; kf < 4; ++kf) {
            short8 B = *(const short8*)(plds + col * 128 + (((kf * 4 + hi) ^ am) * 8));
            acc = __builtin_amdgcn_mfma_f32_16x16x32_bf16(A[kf], B, acc, 0, 0, 0);
        }
        float b = b_proj[col];
#pragma unroll
        for (int r = 0; r < 4; ++r) {
            int grow = crow0 + r;
            if (grow < N) hv16[(size_t)grow * 128 + col] = f2b(acc[r] + b);
        }
    }
}

// ---- pass 1 over edges: XCD-binned in-degree counts ----------------------
__global__ void k_edge(
    const int* __restrict__ dst, int* __restrict__ count, int N, int E)
{
    int e = blockIdx.x * blockDim.x + threadIdx.x;
    if (e >= E) return;
    int x = blockIdx.x & 7;                    // bin == XCD if round-robin
    atomicAdd(&count[x * N + dst[e]], 1);
}

// ---- 3-level scan for binned CSR offsets (M = 8N elements) ---------------
__global__ __launch_bounds__(256) void k_scan_local(
    const int* __restrict__ count, int* __restrict__ lex,
    int* __restrict__ bsum, int M)
{
    __shared__ int sdata[256];
    int tid = threadIdx.x;
    int i = blockIdx.x * 256 + tid;
    int v = (i < M) ? count[i] : 0;
    int incl = v;
    sdata[tid] = incl; __syncthreads();
#pragma unroll
    for (int off = 1; off < 256; off <<= 1) {
        int add = (tid >= off) ? sdata[tid - off] : 0;
        __syncthreads();
        incl += add;
        sdata[tid] = incl;
        __syncthreads();
    }
    if (i < M) lex[i] = incl - v;
    if (tid == 255) bsum[blockIdx.x] = incl;
}

__global__ __launch_bounds__(256) void k_scan_blocks(int* __restrict__ bsum, int nb)
{
    __shared__ int sdata[256];
    __shared__ int carry_s;
    int tid = threadIdx.x;
    if (tid == 0) carry_s = 0;
    __syncthreads();
    for (int base = 0; base < nb; base += 256) {
        int i = base + tid;
        int v = (i < nb) ? bsum[i] : 0;
        int incl = v;
        sdata[tid] = incl; __syncthreads();
#pragma unroll
        for (int off = 1; off < 256; off <<= 1) {
            int add = (tid >= off) ? sdata[tid - off] : 0;
            __syncthreads();
            incl += add;
            sdata[tid] = incl;
            __syncthreads();
        }
        int carry = carry_s;
        if (i < nb) bsum[i] = carry + incl - v;   // exclusive
        int total = sdata[255];
        __syncthreads();
        if (tid == 0) carry_s = carry + total;
        __syncthreads();
    }
}

__global__ __launch_bounds__(256) void k_scan_apply(
    const int* __restrict__ lex, const int* __restrict__ bsum,
    int* __restrict__ row_off, int M)
{
    int i = blockIdx.x * 256 + threadIdx.x;
    if (i < M) row_off[i] = lex[i] + bsum[blockIdx.x];
}

// ---- pass 2: fill CSR (XCD-local 8B records + XCD-local den bins) --------
__global__ void k_fill(
    const int* __restrict__ src, const int* __restrict__ dst,
    const float* __restrict__ s_d, const float* __restrict__ s_s,
    const float* __restrict__ b_edge, float* __restrict__ den8,
    int* __restrict__ row_off, uint2* __restrict__ edge_rec, int N, int E)
{
    int e = blockIdx.x * blockDim.x + threadIdx.x;
    if (e >= E) return;
    int s = src[e], t = dst[e];
    float l = s_d[t] + s_s[s] + b_edge[0];
    l = l > 0.f ? l : 0.01f * l;
    float ev = __expf(l);
    int x = blockIdx.x & 7;                    // must match k_edge's binning
    atomicAdd(&den8[x * N + t], ev);           // XCD-local line
    int pos = atomicAdd(&row_off[x * N + t], 1);
    uint2 rec;
    rec.x = (uint_t)s;
    rec.y = __float_as_uint(ev);
    edge_rec[pos] = rec;
}

// ---- aggregate: LDS-staged edge list, 4-deep pipelined row gathers -------
__global__ __launch_bounds__(256) void k_agg3(
    const ushort_t* __restrict__ hv16, const int* __restrict__ row_end,
    const int* __restrict__ count, const float* __restrict__ den8,
    const uint2* __restrict__ edge_rec, ushort_t* __restrict__ ctx16, int N)
{
    __shared__ uint2 elds[4][128];             // 4 nodes x <=128 edges = 4 KB
    int w = threadIdx.x >> 6, lane = threadIdx.x & 63;
    int v = blockIdx.x * 4 + w;
    bool vok = v < N;

    int begs[8], cnts[8];
    int total = 0;
    float dv = 0.f;
    if (vok) {
#pragma unroll
        for (int x = 0; x < 8; ++x) {
            int i = x * N + v;
            int end = row_end[i];              // wave-uniform scalar loads
            int cnt = count[i];
            begs[x] = end - cnt;
            cnts[x] = cnt;
            dv += den8[i];
        }
#pragma unroll
        for (int x = 0; x < 8; ++x) {
            for (int c = lane; c < cnts[x]; c += 64) {
                int idx = total + c;
                if (idx < 128) elds[w][idx] = edge_rec[begs[x] + c];
            }
            total += cnts[x];
        }
    }
    float inv = dv > 0.f ? 1.f / dv : 0.f;

    float c0 = 0.f, c1 = 0.f;
    int cap = min(total, 128);
    for (int t0 = 0; t0 < cap; t0 += 4) {
        uint_t p[4];
        float wt[4];
#pragma unroll
        for (int k = 0; k < 4; ++k) {
            int tt = t0 + k;
            uint2 er = elds[w][tt < cap ? tt : 0];
            wt[k] = (tt < cap) ? fmaf(__uint_as_float(er.y), inv, 1.0f) : 0.f;
            p[k] = ((const uint_t*)(hv16 + ((size_t)er.x << 7)))[lane];
        }
#pragma unroll
        for (int k = 0; k < 4; ++k) {
            c0 = fmaf(b2f((ushort_t)p[k]), wt[k], c0);
            c1 = fmaf(b2f((ushort_t)(p[k] >> 16)), wt[k], c1);
        }
    }
    if (total > 128) {                         // ~never taken (deg>128)
        int flat = 0;
#pragma unroll 1
        for (int x = 0; x < 8; ++x) {
            for (int c = 0; c < cnts[x]; ++c) {
                if (flat + c >= 128) {
                    uint2 er = edge_rec[begs[x] + c];
                    float wt2 = fmaf(__uint_as_float(er.y), inv, 1.0f);
                    uint_t p2 = ((const uint_t*)(hv16 + ((size_t)er.x << 7)))[lane];
                    c0 = fmaf(b2f((ushort_t)p2), wt2, c0);
                    c1 = fmaf(b2f((ushort_t)(p2 >> 16)), wt2, c1);
                }
            }
            flat += cnts[x];
        }
    }
    if (!vok) return;
    c0 = c0 > 0.f ? c0 : expm1f(c0);
    c1 = c1 > 0.f ? c1 : expm1f(c1);
    uint_t packed = (uint_t)f2b(c0) | ((uint_t)f2b(c1) << 16);
    ((uint_t*)ctx16)[(size_t)v * 64 + lane] = packed;
}

// ---- fused GRU + relu + BN-stats (weights double-buffered in LDS) --------
__global__ __launch_bounds__(256, 2) void k_gru_mfma(
    const ushort_t* __restrict__ ctx16, const ushort_t* __restrict__ nf16,
    const ushort_t* __restrict__ Wih16, const ushort_t* __restrict__ Whh16,
    const float* __restrict__ b_ih, const float* __restrict__ b_hh,
    float* __restrict__ out, float* __restrict__ bn, int N)
{
    __shared__ ushort_t wlds[2 * 12288];   // 48 KB
    __shared__ float bnsum[2][4][128];     // 4 KB
    int w = threadIdx.x >> 6, lane = threadIdx.x & 63;
    int am = lane & 15, hi = lane >> 4, ak = hi * 8;
    int r0 = blockIdx.x * 128 + w * 32;

    for (int i = threadIdx.x; i < 1024; i += 256)
        ((float*)bnsum)[i] = 0.f;

    short8 st[6];
    auto stage_load = [&](int cb) {
#pragma unroll
        for (int i = 0; i < 6; ++i) {
            int ch = w * 6 + i, m = ch >> 2, g = ch & 3;
            int dloc = g * 4 + hi;
            int wrow = (m >> 1) * 128 + cb * 16 + dloc;
            const ushort_t* sb = (m & 1) ? Whh16 : Wih16;
            st[i] = *(const short8*)(sb + (size_t)wrow * 128 + am * 8);
        }
    };
    auto stage_write = [&](int buf) {
#pragma unroll
        for (int i = 0; i < 6; ++i) {
            int ch = w * 6 + i, m = ch >> 2, g = ch & 3;
            int dloc = g * 4 + hi;
            *(short8*)(wlds + buf * 12288 + m * 2048 + dloc * 128 + ((am ^ dloc) * 8)) = st[i];
        }
    };

    stage_load(0);
    stage_write(0);

    short8 Ac[2][4], An[2][4];
#pragma unroll
    for (int rf = 0; rf < 2; ++rf) {
        int arow = r0 + rf * 16 + am;
        bool aok = arow < N;
        short8 z = {0,0,0,0,0,0,0,0};
#pragma unroll
        for (int kf = 0; kf < 4; ++kf) {
            size_t off = (size_t)arow * 128 + kf * 32 + ak;
            Ac[rf][kf] = aok ? *(const short8*)(ctx16 + off) : z;
            An[rf][kf] = aok ? *(const short8*)(nf16 + off) : z;
        }
    }

#pragma unroll 1
    for (int c = 0; c < 8; ++c) {
        __syncthreads();                       // buf[c&1] fully written
        int buf = c & 1;
        if (c < 7) stage_load(c + 1);

        int d = c * 16 + am;
        f32x4 racc[2], zacc[2], iacc[2], hacc[2];
#pragma unroll
        for (int rf = 0; rf < 2; ++rf) {
            racc[rf] = (f32x4){0.f,0.f,0.f,0.f};
            zacc[rf] = (f32x4){0.f,0.f,0.f,0.f};
            iacc[rf] = (f32x4){0.f,0.f,0.f,0.f};
            hacc[rf] = (f32x4){0.f,0.f,0.f,0.f};
        }
#pragma unroll
        for (int kf = 0; kf < 4; ++kf) {
            const ushort_t* bp = wlds + buf * 12288 + am * 128
                               + (((kf * 4 + hi) ^ am) * 8);
            short8 Br = *(const short8*)(bp + 0 * 2048);
            short8 Cr = *(const short8*)(bp + 1 * 2048);
            short8 Bz = *(const short8*)(bp + 2 * 2048);
            short8 Cz = *(const short8*)(bp + 3 * 2048);
            short8 Bi = *(const short8*)(bp + 4 * 2048);
            short8 Ch = *(const short8*)(bp + 5 * 2048);
#pragma unroll
            for (int rf = 0; rf < 2; ++rf) {
                racc[rf] = __builtin_amdgcn_mfma_f32_16x16x32_bf16(Ac[rf][kf], Br, racc[rf], 0, 0, 0);
                racc[rf] = __builtin_amdgcn_mfma_f32_16x16x32_bf16(An[rf][kf], Cr, racc[rf], 0, 0, 0);
                zacc[rf] = __builtin_amdgcn_mfma_f32_16x16x32_bf16(Ac[rf][kf], Bz, zacc[rf], 0, 0, 0);
                zacc[rf] = __builtin_amdgcn_mfma_f32_16x16x32_bf16(An[rf][kf], Cz, zacc[rf], 0, 0, 0);
                iacc[rf] = __builtin_amdgcn_mfma_f32_16x16x32_bf16(Ac[rf][kf], Bi, iacc[rf], 0, 0, 0);
                hacc[rf] = __builtin_amdgcn_mfma_f32_16x16x32_bf16(An[rf][kf], Ch, hacc[rf], 0, 0, 0);
            }
        }
        float br = b_ih[d] + b_hh[d];
        float bz = b_ih[128 + d] + b_hh[128 + d];
        float bi = b_ih[256 + d];
        float bh = b_hh[256 + d];
        float cs = 0.f, cs2 = 0.f;
#pragma unroll
        for (int rf = 0; rf < 2; ++rf) {
            int crow0 = r0 + rf * 16 + hi * 4;
#pragma unroll
            for (int r = 0; r < 4; ++r) {
                int grow = crow0 + r;
                if (grow >= N) continue;
                float rv = sigm(racc[rf][r] + br);
                float zv = sigm(zacc[rf][r] + bz);
                float nv = tanh_(iacc[rf][r] + bi + rv * (hacc[rf][r] + bh));
                float hp = b2f(nf16[(size_t)grow * 128 + d]);
                float h = (1.f - zv) * nv + zv * hp;
                h = fmaxf(h, 0.f);
                out[(size_t)grow * 128 + d] = h;
                cs += h;
                cs2 = fmaf(h, h, cs2);
            }
        }
        cs  += __shfl_xor(cs, 16);  cs  += __shfl_xor(cs, 32);
        cs2 += __shfl_xor(cs2, 16); cs2 += __shfl_xor(cs2, 32);
        if (hi == 0) {
            bnsum[0][w][d] += cs;
            bnsum[1][w][d] += cs2;
        }
        __syncthreads();                       // everyone done reading buf
        if (c < 7) stage_write(buf ^ 1);
    }
    __syncthreads();
    int t = threadIdx.x;
    if (t < 128) {
        float s = bnsum[0][0][t] + bnsum[0][1][t] + bnsum[0][2][t] + bnsum[0][3][t];
        atomicAdd(&bn[t], s);
    } else {
        int d2 = t - 128;
        float s2 = bnsum[1][0][d2] + bnsum[1][1][d2] + bnsum[1][2][d2] + bnsum[1][3][d2];
        atomicAdd(&bn[128 + d2], s2);
    }
}

// ---- BatchNorm normalize -------------------------------------------------
__global__ __launch_bounds__(256) void k_bnnorm(
    float* __restrict__ out, const float* __restrict__ bn,
    const float* __restrict__ gamma, const float* __restrict__ beta, int N)
{
    int idx = blockIdx.x * 256 + threadIdx.x;
    int total = N * 128;
    if (idx >= total) return;
    int d = idx & 127;
    float invN = 1.f / (float)N;
    float mean = bn[d] * invN;
    float var = bn[128 + d] * invN - mean * mean;
    float inv_std = rsqrtf(var + 1e-5f);
    float x = out[idx];
    out[idx] = (x - mean) * inv_std * gamma[d] + beta[d];
}

// ---- host launcher -------------------------------------------------------
extern "C" void kernel_launch(void* const* d_in, const int* in_sizes, int n_in,
                              void* d_out, int out_size, void* d_ws, size_t ws_size,
                              hipStream_t stream)
{
    const float* nf     = (const float*)d_in[0];
    const int*   src    = (const int*)  d_in[1];
    const int*   dst    = (const int*)  d_in[2];
    const float* W_edge = (const float*)d_in[3];
    const float* b_edge = (const float*)d_in[4];
    const float* W_proj = (const float*)d_in[5];
    const float* b_proj = (const float*)d_in[6];
    const float* W_ih   = (const float*)d_in[7];
    const float* W_hh   = (const float*)d_in[8];
    const float* b_ih   = (const float*)d_in[9];
    const float* b_hh   = (const float*)d_in[10];
    const float* bn_g   = (const float*)d_in[11];
    const float* bn_b   = (const float*)d_in[12];

    const int N = in_sizes[0] / D;   // 50000
    const int E = in_sizes[1];       // 600000
    const int M = 8 * N;             // binned count/offset array length

    float* ws = (float*)d_ws;
    float* s_d       = ws;                                  // N
    float* s_s       = ws + (size_t)N;                      // N
    float* den8      = ws + (size_t)2 * N;                  // 8N (XCD-binned)
    int*   count     = (int*)(ws + (size_t)10 * N);         // 8N
    int*   row_off   = (int*)(ws + (size_t)18 * N);         // 8N (seg-end after fill)
    int*   lex       = (int*)(ws + (size_t)26 * N);         // 8N
    float* bn        = ws + (size_t)34 * N;                 // 256
    int*   bsum      = (int*)(bn + 256);                    // 2048
    uint2* edge_rec  = (uint2*)(bsum + 2048);               // E * 8B
    ushort_t* nf16   = (ushort_t*)(edge_rec + (size_t)E);
    ushort_t* hv16   = nf16 + (size_t)N * 128;
    ushort_t* ctx16  = hv16 + (size_t)N * 128;
    ushort_t* Wih16  = ctx16 + (size_t)N * 128;
    ushort_t* Whh16  = Wih16 + 384 * 128;
    ushort_t* WpT16  = Whh16 + 384 * 128;

    float* outp = (float*)d_out;

    // den8 (8N floats) + count (8N ints) contiguous -> one memset
    hipMemsetAsync(den8, 0, (size_t)16 * N * sizeof(float), stream);
    hipMemsetAsync(bn, 0, 256 * sizeof(float), stream);

    int nb_scan = (M + 255) / 256;   // 1563 (<= 2048 bsum slots)

    k_prep_w<<<(114688 + 255) / 256, 256, 0, stream>>>(W_ih, W_hh, W_proj,
                                                       Wih16, Whh16, WpT16);
    k_hv_fused<<<(N + 63) / 64, 256, 0, stream>>>(nf, WpT16, b_proj, W_edge,
                                                  nf16, hv16, s_d, s_s, N);
    k_edge<<<(E + 255) / 256, 256, 0, stream>>>(dst, count, N, E);
    k_scan_local<<<nb_scan, 256, 0, stream>>>(count, lex, bsum, M);
    k_scan_blocks<<<1, 256, 0, stream>>>(bsum, nb_scan);
    k_scan_apply<<<nb_scan, 256, 0, stream>>>(lex, bsum, row_off, M);
    k_fill<<<(E + 255) / 256, 256, 0, stream>>>(src, dst, s_d, s_s, b_edge,
                                                den8, row_off, edge_rec, N, E);
    k_agg3<<<(N + 3) / 4, 256, 0, stream>>>(hv16, row_off, count, den8,
                                            edge_rec, ctx16, N);
    k_gru_mfma<<<(N + 127) / 128, 256, 0, stream>>>(ctx16, nf16, Wih16, Whh16,
                                                    b_ih, b_hh, outp, bn, N);
    k_bnnorm<<<(N * D + 255) / 256, 256, 0, stream>>>(outp, bn, bn_g, bn_b, N);
}

// Round 10
// 157.955 us; speedup vs baseline: 1.4903x; 1.4405x over previous
//
#include <hip/hip_runtime.h>
#include <math.h>

constexpr int D = 128;

typedef __attribute__((ext_vector_type(8))) short short8;
typedef __attribute__((ext_vector_type(4))) float f32x4;
typedef unsigned short ushort_t;
typedef unsigned int uint_t;

__device__ inline ushort_t f2b(float x) {          // fp32 -> bf16 RNE
    uint_t u = __float_as_uint(x);
    uint_t r = u + 0x7fffu + ((u >> 16) & 1u);
    return (ushort_t)(r >> 16);
}
__device__ inline float b2f(ushort_t b) { return __uint_as_float(((uint_t)b) << 16); }

__device__ inline float sigm(float x) { return 1.f / (1.f + __expf(-x)); }
__device__ inline float tanh_(float x) {
    float t = __expf(-2.f * fabsf(x));
    float y = (1.f - t) / (1.f + t);
    return x >= 0.f ? y : -y;
}

// ---- convert weights to bf16 ---------------------------------------------
__global__ __launch_bounds__(256) void k_prep_w(
    const float* __restrict__ W_ih, const float* __restrict__ W_hh,
    const float* __restrict__ W_proj,
    ushort_t* __restrict__ Wih16, ushort_t* __restrict__ Whh16,
    ushort_t* __restrict__ WpT16)
{
    int idx = blockIdx.x * 256 + threadIdx.x;
    if (idx < 49152) {
        Wih16[idx] = f2b(W_ih[idx]);
    } else if (idx < 98304) {
        int i = idx - 49152;
        Whh16[i] = f2b(W_hh[i]);
    } else if (idx < 114688) {
        int t = idx - 98304;           // WpT[j][k] = W_proj[k][j]
        int j = t >> 7, k = t & 127;
        WpT16[t] = f2b(W_proj[k * 128 + j]);
    }
}

// ---- fused: nf->bf16, edge scores, hv16 = bf16(nf@WpT+b) (MFMA) ----------
__global__ __launch_bounds__(256, 2) void k_hv_fused(
    const float* __restrict__ nf, const ushort_t* __restrict__ WpT16,
    const float* __restrict__ b_proj, const float* __restrict__ W_edge,
    ushort_t* __restrict__ nf16, ushort_t* __restrict__ hv16,
    float* __restrict__ s_d, float* __restrict__ s_s, int N)
{
    __shared__ ushort_t plds[16384];           // 128 x 128 bf16 = 32 KB
    int w = threadIdx.x >> 6, lane = threadIdx.x & 63;
    int am = lane & 15, hi = lane >> 4, ak = hi * 8;

#pragma unroll
    for (int i = 0; i < 8; ++i) {
        int dl = (w * 8 + i) * 4 + hi;         // 0..127
        short8 v = *(const short8*)(WpT16 + (size_t)dl * 128 + am * 8);
        *(short8*)(plds + dl * 128 + ((am ^ (dl & 15)) * 8)) = v;
    }

    int r0 = blockIdx.x * 64 + w * 16;
    int arow = r0 + am;
    bool aok = arow < N;
    short8 A[4];
    float pd = 0.f, ps = 0.f;
#pragma unroll
    for (int kf = 0; kf < 4; ++kf) {
        int ko = kf * 32 + ak;
        float4 f0 = {0,0,0,0}, f1 = {0,0,0,0};
        if (aok) {
            f0 = *(const float4*)(nf + (size_t)arow * 128 + ko);
            f1 = *(const float4*)(nf + (size_t)arow * 128 + ko + 4);
        }
        pd += f0.x * W_edge[ko]     + f0.y * W_edge[ko + 1]
            + f0.z * W_edge[ko + 2] + f0.w * W_edge[ko + 3]
            + f1.x * W_edge[ko + 4] + f1.y * W_edge[ko + 5]
            + f1.z * W_edge[ko + 6] + f1.w * W_edge[ko + 7];
        ps += f0.x * W_edge[128+ko]     + f0.y * W_edge[128+ko+1]
            + f0.z * W_edge[128+ko+2]   + f0.w * W_edge[128+ko+3]
            + f1.x * W_edge[128+ko+4]   + f1.y * W_edge[128+ko+5]
            + f1.z * W_edge[128+ko+6]   + f1.w * W_edge[128+ko+7];
        short8 a;
        a[0] = (short)f2b(f0.x); a[1] = (short)f2b(f0.y);
        a[2] = (short)f2b(f0.z); a[3] = (short)f2b(f0.w);
        a[4] = (short)f2b(f1.x); a[5] = (short)f2b(f1.y);
        a[6] = (short)f2b(f1.z); a[7] = (short)f2b(f1.w);
        A[kf] = a;
        if (aok) *(short8*)(nf16 + (size_t)arow * 128 + ko) = a;
    }
    pd += __shfl_xor(pd, 16); pd += __shfl_xor(pd, 32);
    ps += __shfl_xor(ps, 16); ps += __shfl_xor(ps, 32);
    if (hi == 0 && aok) { s_d[arow] = pd; s_s[arow] = ps; }

    __syncthreads();                           // LDS weights ready

    int crow0 = r0 + hi * 4;
#pragma unroll 1
    for (int nc = 0; nc < 8; ++nc) {
        f32x4 acc = {0.f, 0.f, 0.f, 0.f};
        int col = nc * 16 + am;
#pragma unroll
        for (int kf = 0; kf < 4; ++kf) {
            short8 B = *(const short8*)(plds + col * 128 + (((kf * 4 + hi) ^ am) * 8));
            acc = __builtin_amdgcn_mfma_f32_16x16x32_bf16(A[kf], B, acc, 0, 0, 0);
        }
        float b = b_proj[col];
#pragma unroll
        for (int r = 0; r < 4; ++r) {
            int grow = crow0 + r;
            if (grow < N) hv16[(size_t)grow * 128 + col] = f2b(acc[r] + b);
        }
    }
}

// ---- bucket histogram (bucket = dst>>8), LDS-first -----------------------
__global__ __launch_bounds__(256) void k_edge_b(
    const int* __restrict__ dst, int* __restrict__ bcnt, int NBK, int E)
{
    __shared__ int h[256];
    for (int i = threadIdx.x; i < NBK; i += 256) h[i] = 0;
    __syncthreads();
    for (int e = blockIdx.x * 256 + threadIdx.x; e < E; e += gridDim.x * 256)
        atomicAdd(&h[dst[e] >> 8], 1);
    __syncthreads();
    for (int i = threadIdx.x; i < NBK; i += 256)
        if (h[i]) atomicAdd(&bcnt[i], h[i]);
}

// ---- single-block scan of bucket counts ----------------------------------
__global__ __launch_bounds__(256) void k_scan_b(
    const int* __restrict__ bcnt, int* __restrict__ bbase,
    int* __restrict__ gcur, int NBK)
{
    __shared__ int sdata[256];
    int tid = threadIdx.x;
    int v = (tid < NBK) ? bcnt[tid] : 0;
    int incl = v;
    sdata[tid] = incl; __syncthreads();
#pragma unroll
    for (int off = 1; off < 256; off <<= 1) {
        int add = (tid >= off) ? sdata[tid - off] : 0;
        __syncthreads();
        incl += add;
        sdata[tid] = incl;
        __syncthreads();
    }
    if (tid < NBK) {
        bbase[tid] = incl - v;
        gcur[tid] = incl - v;
    }
    if (tid == NBK - 1) bbase[NBK] = incl;     // = E
}

// ---- phase 1: partition edges into buckets (write-combined runs) ---------
// record: src | (dst&255)<<16   (requires N <= 65536; N = 50000)
constexpr int EPT = 16;                        // edges per thread
__global__ __launch_bounds__(256) void k_part(
    const int* __restrict__ src, const int* __restrict__ dst,
    int* __restrict__ gcur, uint_t* __restrict__ pre_rec, int NBK, int E)
{
    __shared__ int cnt[256];
    __shared__ int gbase[256];
    int tid = threadIdx.x;
    int base = blockIdx.x * (256 * EPT);
    for (int i = tid; i < NBK; i += 256) cnt[i] = 0;
    __syncthreads();
    uint_t rec[EPT], pw[EPT];
#pragma unroll
    for (int i = 0; i < EPT; ++i) {
        int e = base + i * 256 + tid;
        uint_t r = 0, p = 0xFFFFFFFFu;
        if (e < E) {
            int s = src[e], t = dst[e];
            int b = t >> 8;
            int old = atomicAdd(&cnt[b], 1);
            r = (uint_t)s | ((uint_t)(t & 255) << 16);
            p = ((uint_t)b << 16) | (uint_t)old;
        }
        rec[i] = r; pw[i] = p;
    }
    __syncthreads();
    for (int bkt = tid; bkt < NBK; bkt += 256) {
        int c = cnt[bkt];
        gbase[bkt] = c ? atomicAdd(&gcur[bkt], c) : 0;
    }
    __syncthreads();
#pragma unroll
    for (int i = 0; i < EPT; ++i) {
        if (pw[i] != 0xFFFFFFFFu) {
            int b = pw[i] >> 16;
            int old = pw[i] & 0xFFFF;
            pre_rec[gbase[b] + old] = rec[i];
        }
    }
}

// ---- phase 2: per-bucket node sort + ev/den + CSR write ------------------
__global__ __launch_bounds__(256) void k_bucket(
    const uint_t* __restrict__ pre_rec, const int* __restrict__ bbase,
    const float* __restrict__ s_d, const float* __restrict__ s_s,
    const float* __restrict__ b_edge,
    int* __restrict__ row_start, uint2* __restrict__ edge_rec,
    float* __restrict__ den, int N, int E)
{
    __shared__ int cnt[256], offx[256], cur[256], sdata[256];
    __shared__ float sdl[256], denl[256];
    int b = blockIdx.x, tid = threadIdx.x;
    int node = (b << 8) + tid;
    cnt[tid] = 0; cur[tid] = 0; denl[tid] = 0.f;
    sdl[tid] = (node < N) ? s_d[node] : 0.f;
    __syncthreads();
    int rs0 = bbase[b], rs1 = bbase[b + 1];
    for (int i = rs0 + tid; i < rs1; i += 256)
        atomicAdd(&cnt[(pre_rec[i] >> 16) & 255], 1);
    __syncthreads();
    int v = cnt[tid];
    int incl = v;
    sdata[tid] = incl; __syncthreads();
#pragma unroll
    for (int off = 1; off < 256; off <<= 1) {
        int add = (tid >= off) ? sdata[tid - off] : 0;
        __syncthreads();
        incl += add;
        sdata[tid] = incl;
        __syncthreads();
    }
    offx[tid] = incl - v;
    if (node < N) row_start[node] = rs0 + incl - v;
    if (b == gridDim.x - 1 && tid == 0) row_start[N] = E;
    __syncthreads();
    float bias = b_edge[0];
    for (int i = rs0 + tid; i < rs1; i += 256) {
        uint_t rec = pre_rec[i];
        int sidx = rec & 0xFFFF;
        int dl = (rec >> 16) & 255;
        float l = sdl[dl] + s_s[sidx] + bias;
        l = l > 0.f ? l : 0.01f * l;
        float ev = __expf(l);
        int lp = atomicAdd(&cur[dl], 1);
        uint2 r;
        r.x = (uint_t)sidx;
        r.y = __float_as_uint(ev);
        edge_rec[rs0 + offx[dl] + lp] = r;
        atomicAdd(&denl[dl], ev);
    }
    __syncthreads();
    if (node < N) den[node] = denl[tid];
}

// ---- aggregate: LDS-staged edge list, 4-deep pipelined row gathers -------
__global__ __launch_bounds__(256) void k_agg3(
    const ushort_t* __restrict__ hv16, const int* __restrict__ row_start,
    const float* __restrict__ den, const uint2* __restrict__ edge_rec,
    ushort_t* __restrict__ ctx16, int N)
{
    __shared__ uint2 elds[4][128];             // 4 nodes x <=128 edges = 4 KB
    int w = threadIdx.x >> 6, lane = threadIdx.x & 63;
    int v = blockIdx.x * 4 + w;
    bool vok = v < N;

    int beg = 0, cnt = 0;
    float dv = 0.f;
    if (vok) {
        beg = row_start[v];
        cnt = row_start[v + 1] - beg;
        dv = den[v];
        int cap0 = min(cnt, 128);
        for (int c = lane; c < cap0; c += 64)
            elds[w][c] = edge_rec[beg + c];
    }
    float inv = dv > 0.f ? 1.f / dv : 0.f;

    float c0 = 0.f, c1 = 0.f;
    int cap = min(cnt, 128);
    for (int t0 = 0; t0 < cap; t0 += 4) {
        uint_t p[4];
        float wt[4];
#pragma unroll
        for (int k = 0; k < 4; ++k) {
            int tt = t0 + k;
            uint2 er = elds[w][tt < cap ? tt : 0];
            wt[k] = (tt < cap) ? fmaf(__uint_as_float(er.y), inv, 1.0f) : 0.f;
            p[k] = ((const uint_t*)(hv16 + ((size_t)er.x << 7)))[lane];
        }
#pragma unroll
        for (int k = 0; k < 4; ++k) {
            c0 = fmaf(b2f((ushort_t)p[k]), wt[k], c0);
            c1 = fmaf(b2f((ushort_t)(p[k] >> 16)), wt[k], c1);
        }
    }
    for (int c = 128; c < cnt; ++c) {          // ~never taken (deg>128)
        uint2 er = edge_rec[beg + c];
        float wt2 = fmaf(__uint_as_float(er.y), inv, 1.0f);
        uint_t p2 = ((const uint_t*)(hv16 + ((size_t)er.x << 7)))[lane];
        c0 = fmaf(b2f((ushort_t)p2), wt2, c0);
        c1 = fmaf(b2f((ushort_t)(p2 >> 16)), wt2, c1);
    }
    if (!vok) return;
    c0 = c0 > 0.f ? c0 : expm1f(c0);
    c1 = c1 > 0.f ? c1 : expm1f(c1);
    uint_t packed = (uint_t)f2b(c0) | ((uint_t)f2b(c1) << 16);
    ((uint_t*)ctx16)[(size_t)v * 64 + lane] = packed;
}

// ---- fused GRU + relu + BN-stats (weights double-buffered in LDS) --------
__global__ __launch_bounds__(256, 2) void k_gru_mfma(
    const ushort_t* __restrict__ ctx16, const ushort_t* __restrict__ nf16,
    const ushort_t* __restrict__ Wih16, const ushort_t* __restrict__ Whh16,
    const float* __restrict__ b_ih, const float* __restrict__ b_hh,
    float* __restrict__ out, float* __restrict__ bn, int N)
{
    __shared__ ushort_t wlds[2 * 12288];   // 48 KB
    __shared__ float bnsum[2][4][128];     // 4 KB
    int w = threadIdx.x >> 6, lane = threadIdx.x & 63;
    int am = lane & 15, hi = lane >> 4, ak = hi * 8;
    int r0 = blockIdx.x * 128 + w * 32;

    for (int i = threadIdx.x; i < 1024; i += 256)
        ((float*)bnsum)[i] = 0.f;

    short8 st[6];
    auto stage_load = [&](int cb) {
#pragma unroll
        for (int i = 0; i < 6; ++i) {
            int ch = w * 6 + i, m = ch >> 2, g = ch & 3;
            int dloc = g * 4 + hi;
            int wrow = (m >> 1) * 128 + cb * 16 + dloc;
            const ushort_t* sb = (m & 1) ? Whh16 : Wih16;
            st[i] = *(const short8*)(sb + (size_t)wrow * 128 + am * 8);
        }
    };
    auto stage_write = [&](int buf) {
#pragma unroll
        for (int i = 0; i < 6; ++i) {
            int ch = w * 6 + i, m = ch >> 2, g = ch & 3;
            int dloc = g * 4 + hi;
            *(short8*)(wlds + buf * 12288 + m * 2048 + dloc * 128 + ((am ^ dloc) * 8)) = st[i];
        }
    };

    stage_load(0);
    stage_write(0);

    short8 Ac[2][4], An[2][4];
#pragma unroll
    for (int rf = 0; rf < 2; ++rf) {
        int arow = r0 + rf * 16 + am;
        bool aok = arow < N;
        short8 z = {0,0,0,0,0,0,0,0};
#pragma unroll
        for (int kf = 0; kf < 4; ++kf) {
            size_t off = (size_t)arow * 128 + kf * 32 + ak;
            Ac[rf][kf] = aok ? *(const short8*)(ctx16 + off) : z;
            An[rf][kf] = aok ? *(const short8*)(nf16 + off) : z;
        }
    }

#pragma unroll 1
    for (int c = 0; c < 8; ++c) {
        __syncthreads();                       // buf[c&1] fully written
        int buf = c & 1;
        if (c < 7) stage_load(c + 1);

        int d = c * 16 + am;
        f32x4 racc[2], zacc[2], iacc[2], hacc[2];
#pragma unroll
        for (int rf = 0; rf < 2; ++rf) {
            racc[rf] = (f32x4){0.f,0.f,0.f,0.f};
            zacc[rf] = (f32x4){0.f,0.f,0.f,0.f};
            iacc[rf] = (f32x4){0.f,0.f,0.f,0.f};
            hacc[rf] = (f32x4){0.f,0.f,0.f,0.f};
        }
#pragma unroll
        for (int kf = 0; kf < 4; ++kf) {
            const ushort_t* bp = wlds + buf * 12288 + am * 128
                               + (((kf * 4 + hi) ^ am) * 8);
            short8 Br = *(const short8*)(bp + 0 * 2048);
            short8 Cr = *(const short8*)(bp + 1 * 2048);
            short8 Bz = *(const short8*)(bp + 2 * 2048);
            short8 Cz = *(const short8*)(bp + 3 * 2048);
            short8 Bi = *(const short8*)(bp + 4 * 2048);
            short8 Ch = *(const short8*)(bp + 5 * 2048);
#pragma unroll
            for (int rf = 0; rf < 2; ++rf) {
                racc[rf] = __builtin_amdgcn_mfma_f32_16x16x32_bf16(Ac[rf][kf], Br, racc[rf], 0, 0, 0);
                racc[rf] = __builtin_amdgcn_mfma_f32_16x16x32_bf16(An[rf][kf], Cr, racc[rf], 0, 0, 0);
                zacc[rf] = __builtin_amdgcn_mfma_f32_16x16x32_bf16(Ac[rf][kf], Bz, zacc[rf], 0, 0, 0);
                zacc[rf] = __builtin_amdgcn_mfma_f32_16x16x32_bf16(An[rf][kf], Cz, zacc[rf], 0, 0, 0);
                iacc[rf] = __builtin_amdgcn_mfma_f32_16x16x32_bf16(Ac[rf][kf], Bi, iacc[rf], 0, 0, 0);
                hacc[rf] = __builtin_amdgcn_mfma_f32_16x16x32_bf16(An[rf][kf], Ch, hacc[rf], 0, 0, 0);
            }
        }
        float br = b_ih[d] + b_hh[d];
        float bz = b_ih[128 + d] + b_hh[128 + d];
        float bi = b_ih[256 + d];
        float bh = b_hh[256 + d];
        float cs = 0.f, cs2 = 0.f;
#pragma unroll
        for (int rf = 0; rf < 2; ++rf) {
            int crow0 = r0 + rf * 16 + hi * 4;
#pragma unroll
            for (int r = 0; r < 4; ++r) {
                int grow = crow0 + r;
                if (grow >= N) continue;
                float rv = sigm(racc[rf][r] + br);
                float zv = sigm(zacc[rf][r] + bz);
                float nv = tanh_(iacc[rf][r] + bi + rv * (hacc[rf][r] + bh));
                float hp = b2f(nf16[(size_t)grow * 128 + d]);
                float h = (1.f - zv) * nv + zv * hp;
                h = fmaxf(h, 0.f);
                out[(size_t)grow * 128 + d] = h;
                cs += h;
                cs2 = fmaf(h, h, cs2);
            }
        }
        cs  += __shfl_xor(cs, 16);  cs  += __shfl_xor(cs, 32);
        cs2 += __shfl_xor(cs2, 16); cs2 += __shfl_xor(cs2, 32);
        if (hi == 0) {
            bnsum[0][w][d] += cs;
            bnsum[1][w][d] += cs2;
        }
        __syncthreads();                       // everyone done reading buf
        if (c < 7) stage_write(buf ^ 1);
    }
    __syncthreads();
    int t = threadIdx.x;
    if (t < 128) {
        float s = bnsum[0][0][t] + bnsum[0][1][t] + bnsum[0][2][t] + bnsum[0][3][t];
        atomicAdd(&bn[t], s);
    } else {
        int d2 = t - 128;
        float s2 = bnsum[1][0][d2] + bnsum[1][1][d2] + bnsum[1][2][d2] + bnsum[1][3][d2];
        atomicAdd(&bn[128 + d2], s2);
    }
}

// ---- BatchNorm normalize -------------------------------------------------
__global__ __launch_bounds__(256) void k_bnnorm(
    float* __restrict__ out, const float* __restrict__ bn,
    const float* __restrict__ gamma, const float* __restrict__ beta, int N)
{
    int idx = blockIdx.x * 256 + threadIdx.x;
    int total = N * 128;
    if (idx >= total) return;
    int d = idx & 127;
    float invN = 1.f / (float)N;
    float mean = bn[d] * invN;
    float var = bn[128 + d] * invN - mean * mean;
    float inv_std = rsqrtf(var + 1e-5f);
    float x = out[idx];
    out[idx] = (x - mean) * inv_std * gamma[d] + beta[d];
}

// ---- host launcher -------------------------------------------------------
extern "C" void kernel_launch(void* const* d_in, const int* in_sizes, int n_in,
                              void* d_out, int out_size, void* d_ws, size_t ws_size,
                              hipStream_t stream)
{
    const float* nf     = (const float*)d_in[0];
    const int*   src    = (const int*)  d_in[1];
    const int*   dst    = (const int*)  d_in[2];
    const float* W_edge = (const float*)d_in[3];
    const float* b_edge = (const float*)d_in[4];
    const float* W_proj = (const float*)d_in[5];
    const float* b_proj = (const float*)d_in[6];
    const float* W_ih   = (const float*)d_in[7];
    const float* W_hh   = (const float*)d_in[8];
    const float* b_ih   = (const float*)d_in[9];
    const float* b_hh   = (const float*)d_in[10];
    const float* bn_g   = (const float*)d_in[11];
    const float* bn_b   = (const float*)d_in[12];

    const int N   = in_sizes[0] / D;   // 50000 (must be <= 65536 for 16-bit src)
    const int E   = in_sizes[1];       // 600000
    const int NBK = (N + 255) >> 8;    // 196 buckets

    float* ws = (float*)d_ws;
    float* s_d        = ws;                                 // N
    float* s_s        = ws + (size_t)N;                     // N
    float* den        = ws + (size_t)2 * N;                 // N
    int*   row_start  = (int*)(ws + (size_t)3 * N);         // N+1 (+pad)
    int*   bcnt       = (int*)(ws + (size_t)4 * N + 4);     // 256
    int*   bbase      = (int*)(ws + (size_t)4 * N + 260);   // 257 (+pad)
    int*   gcur       = (int*)(ws + (size_t)4 * N + 520);   // 256
    float* bn         = ws + (size_t)4 * N + 776;           // 256
    uint_t* pre_rec   = (uint_t*)(ws + (size_t)4 * N + 1032);  // E
    uint2*  edge_rec  = (uint2*)(ws + (size_t)4 * N + 1032 + (size_t)E); // E*8B
    ushort_t* nf16    = (ushort_t*)(edge_rec + (size_t)E);
    ushort_t* hv16    = nf16 + (size_t)N * 128;
    ushort_t* ctx16   = hv16 + (size_t)N * 128;
    ushort_t* Wih16   = ctx16 + (size_t)N * 128;
    ushort_t* Whh16   = Wih16 + 384 * 128;
    ushort_t* WpT16   = Whh16 + 384 * 128;

    float* outp = (float*)d_out;

    hipMemsetAsync(bcnt, 0, 256 * sizeof(int), stream);
    hipMemsetAsync(bn, 0, 256 * sizeof(float), stream);

    int nb_part = (E + 256 * EPT - 1) / (256 * EPT);   // 147

    k_prep_w<<<(114688 + 255) / 256, 256, 0, stream>>>(W_ih, W_hh, W_proj,
                                                       Wih16, Whh16, WpT16);
    k_hv_fused<<<(N + 63) / 64, 256, 0, stream>>>(nf, WpT16, b_proj, W_edge,
                                                  nf16, hv16, s_d, s_s, N);
    k_edge_b<<<256, 256, 0, stream>>>(dst, bcnt, NBK, E);
    k_scan_b<<<1, 256, 0, stream>>>(bcnt, bbase, gcur, NBK);
    k_part<<<nb_part, 256, 0, stream>>>(src, dst, gcur, pre_rec, NBK, E);
    k_bucket<<<NBK, 256, 0, stream>>>(pre_rec, bbase, s_d, s_s, b_edge,
                                      row_start, edge_rec, den, N, E);
    k_agg3<<<(N + 3) / 4, 256, 0, stream>>>(hv16, row_start, den,
                                            edge_rec, ctx16, N);
    k_gru_mfma<<<(N + 127) / 128, 256, 0, stream>>>(ctx16, nf16, Wih16, Whh16,
                                                    b_ih, b_hh, outp, bn, N);
    k_bnnorm<<<(N * D + 255) / 256, 256, 0, stream>>>(outp, bn, bn_g, bn_b, N);
}